// Round 8
// baseline (276.408 us; speedup 1.0000x reference)
//
#include <hip/hip_runtime.h>
#include <math.h>

#define RBINS 160
#define BROWS 65536
#define ROWELEMS 480                    // 160 bins * 3 channels
#define ROWF4 120
#define TASKS_PER_ROW 20                // each task: 8 bins x 3 ch = 24 elements
#define NTHREADS 256
#define NBLOCKS_MAIN ((BROWS / 2 * TASKS_PER_ROW) / NTHREADS)  // 2560 (2 rows/thread)
#define NBLOCKS_FIX (BROWS / NTHREADS)                         // 256 (c==0 tasks)

__device__ __forceinline__ float clamp01(float x) {
    return __builtin_amdgcn_fmed3f(x, 0.0f, 1.0f);
}

// One half (12 outputs) of the 4-tap stencil over a 36-float register window.
// P = wave-uniform misalignment (0..3), H = half (0/1). All indices compile-time.
template<int P, int H>
__device__ __forceinline__ void stencil_half(
    const float* __restrict__ w,
    float u1, float u2, float u3, float u4,
    float* __restrict__ r)
{
    #pragma unroll
    for (int m = 0; m < 12; ++m) {
        const int base = P + 12 * H + m;
        float acc = u1 * w[base];
        acc = fmaf(u2, w[base + 3], acc);
        acc = fmaf(u3, w[base + 6], acc);
        acc = fmaf(u4, w[base + 9], acc);
        r[m] = acc;
    }
}

// stencil + fade + 3x float4 store for one half
template<int P, int H>
__device__ __forceinline__ void st12(
    const float* __restrict__ w,
    float u1, float u2, float u3, float u4,
    float* __restrict__ outp, bool fadeq, int bin0)
{
    float r[12];
    stencil_half<P, H>(w, u1, u2, u3, u4, r);
    if (fadeq) {
        #pragma unroll
        for (int mb = 0; mb < 4; ++mb) {
            const int j = bin0 + 4 * H + mb;
            const float t = (float)(RBINS - 1 - j) * 0.125f;
            const float ff = (j >= RBINS - 8) ? t * t : 1.0f;
            r[3*mb+0] *= ff; r[3*mb+1] *= ff; r[3*mb+2] *= ff;
        }
    }
    *(float4*)(outp + 12*H + 0) = make_float4(r[0], r[1], r[2],  r[3]);
    *(float4*)(outp + 12*H + 4) = make_float4(r[4], r[5], r[6],  r[7]);
    *(float4*)(outp + 12*H + 8) = make_float4(r[8], r[9], r[10], r[11]);
}

// mask + clamp over a compile-time subrange [LO,HI) of the window
template<int LO, int HI>
__device__ __forceinline__ void maskclamp(
    float* __restrict__ w, int lo_u, int hi_u)
{
    #pragma unroll
    for (int u = LO; u < HI; ++u) {
        const bool v = (u >= lo_u) && (u < hi_u);
        w[u] = v ? clamp01(w[u]) : 0.0f;
    }
}

// injection over a compile-time subrange (rare path; bench never takes it in main)
template<int LO, int HI>
__device__ __forceinline__ void injseg(
    float* __restrict__ w, int a0,
    const float* __restrict__ color, int b,
    float aw0, float aw1, float aw2, float aw3, float aw4)
{
    const float c0 = color[3*b+0];
    const float c1 = color[3*b+1];
    const float c2 = color[3*b+2];
    #pragma unroll
    for (int u = LO; u < HI; ++u) {
        const int f = a0 + u;
        if ((unsigned)f < 15u) {
            const int bin = f / 3;
            const int ch  = f - 3 * bin;
            const float cv = (ch == 0) ? c0 : (ch == 1) ? c1 : c2;
            const float av = (bin == 0) ? aw0 : (bin == 1) ? aw1 :
                             (bin == 2) ? aw2 : (bin == 3) ? aw3 : aw4;
            w[u] += cv * av;
        }
    }
}

__device__ __forceinline__ void fill24(
    float* __restrict__ w,
    float4 v0, float4 v1, float4 v2, float4 v3, float4 v4, float4 v5)
{
    w[0]=v0.x;  w[1]=v0.y;  w[2]=v0.z;  w[3]=v0.w;
    w[4]=v1.x;  w[5]=v1.y;  w[6]=v1.z;  w[7]=v1.w;
    w[8]=v2.x;  w[9]=v2.y;  w[10]=v2.z; w[11]=v2.w;
    w[12]=v3.x; w[13]=v3.y; w[14]=v3.z; w[15]=v3.w;
    w[16]=v4.x; w[17]=v4.y; w[18]=v4.z; w[19]=v4.w;
    w[20]=v5.x; w[21]=v5.y; w[22]=v5.z; w[23]=v5.w;
}

__device__ __forceinline__ void fillhi(
    float* __restrict__ w, float4 v6, float4 v7, float4 v8)
{
    w[24]=v6.x; w[25]=v6.y; w[26]=v6.z; w[27]=v6.w;
    w[28]=v7.x; w[29]=v7.y; w[30]=v7.z; w[31]=v7.w;
    w[32]=v8.x; w[33]=v8.y; w[34]=v8.z; w[35]=v8.w;
}

// Full pipelined 2-row compute: 4 stages, each stage's VALU covers the
// remaining in-flight loads of the next stage (compiler inserts vmcnt(N)).
template<int P>
__device__ __forceinline__ void pipeline2(
    float4 A0, float4 A1, float4 A2, float4 A3, float4 A4, float4 A5,
    float4 A6, float4 A7, float4 A8,
    float4 B0, float4 B1, float4 B2, float4 B3, float4 B4, float4 B5,
    float4 B6, float4 B7, float4 B8,
    int a0, int Ae, int lo_u, int hi_u,
    float u1, float u2, float u3, float u4,
    bool fadeq, int bin0,
    float* __restrict__ outA, float* __restrict__ outB,
    const float* __restrict__ color, int b0,
    const float* __restrict__ p_amount, const float* __restrict__ p_spread)
{
    // rare-path injection weights (only computed when needed)
    float aw0 = 0, aw1 = 0, aw2 = 0, aw3 = 0, aw4 = 0;
    const bool inj = (Ae < 15);
    if (inj) {
        const float am = fminf(fmaxf(*p_amount, 0.0f), 1.0f);
        const float sp = fminf(fmaxf(*p_spread, 0.0f), 1.0f);
        const float tight = 1.0f - sp;
        aw0 = am * fmaf(0.4f, tight, 0.5f);
        aw1 = am * fmaf(0.2f, sp, 0.05f);
        aw2 = am * (0.12f * sp);
        aw3 = am * (0.06f * sp);
        aw4 = am * (0.02f * sp);
    }

    float wA[36], wB[36];

    // ---- stage 1: A half0 (needs A0..A5 only) ----
    fill24(wA, A0, A1, A2, A3, A4, A5);
    if (inj) injseg<0, 24>(wA, a0, color, b0, aw0, aw1, aw2, aw3, aw4);
    maskclamp<0, 24>(wA, lo_u, hi_u);
    st12<P, 0>(wA, u1, u2, u3, u4, outA, fadeq, bin0);

    // ---- stage 2: B half0 (needs B0..B5; A6..A8,B6..B8 still in flight) ----
    fill24(wB, B0, B1, B2, B3, B4, B5);
    if (inj) injseg<0, 24>(wB, a0, color, b0 + 1, aw0, aw1, aw2, aw3, aw4);
    maskclamp<0, 24>(wB, lo_u, hi_u);
    st12<P, 0>(wB, u1, u2, u3, u4, outB, fadeq, bin0);

    // ---- stage 3: A half1 ----
    fillhi(wA, A6, A7, A8);
    if (inj) injseg<24, 36>(wA, a0, color, b0, aw0, aw1, aw2, aw3, aw4);
    maskclamp<24, 36>(wA, lo_u, hi_u);
    st12<P, 1>(wA, u1, u2, u3, u4, outA, fadeq, bin0);

    // ---- stage 4: B half1 ----
    fillhi(wB, B6, B7, B8);
    if (inj) injseg<24, 36>(wB, a0, color, b0 + 1, aw0, aw1, aw2, aw3, aw4);
    maskclamp<24, 36>(wB, lo_u, hi_u);
    st12<P, 1>(wB, u1, u2, u3, u4, outB, fadeq, bin0);
}

__global__ __launch_bounds__(NTHREADS, 4) void beat_kernel(
    const float* __restrict__ hist,
    const float* __restrict__ color,
    const float* __restrict__ p_offset,
    const float* __restrict__ p_persist,
    const float* __restrict__ p_diff,
    const float* __restrict__ p_dt,
    const float* __restrict__ p_amount,
    const float* __restrict__ p_spread,
    float* __restrict__ out)
{
    // ---- wave-uniform parameter math (mirrors ref f32 ops) ----
    const float offs = *p_offset;
    const float pers = *p_persist;
    const float diff = *p_diff;
    const float dts  = *p_dt;

    const float dt       = fminf(fmaxf(dts, 0.0f), 0.05f);
    const float dt_scale = dt * 60.0f;
    const float s        = offs * dt_scale;
    const float dt_pers  = __powf(pers, dt_scale);
    const int   dfl      = (int)floorf(s);
    const float frac     = s - (float)dfl;    // uniform: floor(i+s)=i+dfl interior
    const float kk = 0.15f * diff;
    const float cc = 1.0f - 2.0f * kk;
    const float wl = (1.0f - frac) * dt_pers;
    const float wr = frac * dt_pers;
    const float u1 = wr * kk;
    const float u2 = fmaf(wl, kk, wr * cc);
    const float u3 = fmaf(wl, cc, wr * kk);
    const float u4 = wl * kk;

    // valid source range as element range [flo, fhi)
    const int ilo = max(0, (int)ceilf(-s));
    const int ihi = min(RBINS - 1, (int)ceilf((float)(RBINS - 1) - s) - 1);
    const int flo = 3 * ilo;
    const int fhi = 3 * ihi + 3;

    if (blockIdx.x < NBLOCKS_MAIN) {
        // ============ main region: 2 rows per thread, pipelined ============
        const int task = blockIdx.x * NTHREADS + threadIdx.x;
        const int pr = task / TASKS_PER_ROW;
        const int c  = task - pr * TASKS_PER_ROW;
        const int b0 = 2 * pr;
        const int e0 = c * 24;
        const int A  = e0 - 6 - 3 * dfl;      // first tap element
        if (A < 15 && c == 0) return;         // fixup blocks own these
        const int p  = A & 3;                 // wave-uniform (dfl-only)
        const int a0 = A - p;
        const int q0 = a0 >> 2;

        // clamped window f4 indices (shared by both rows)
        #define CLQ(q) min(max(q0 + (q), 0), ROWF4 - 1)
        const int i0 = CLQ(0), i1 = CLQ(1), i2 = CLQ(2), i3 = CLQ(3),
                  i4 = CLQ(4), i5 = CLQ(5), i6 = CLQ(6), i7 = CLQ(7), i8 = CLQ(8);
        #undef CLQ

        // ---- 18 independent loads, all issued before any compute ----
        const float4* s0_ = (const float4*)hist + (size_t)b0 * ROWF4;
        const float4* s1_ = s0_ + ROWF4;
        const float4 A0 = s0_[i0], A1 = s0_[i1], A2 = s0_[i2], A3 = s0_[i3],
                     A4 = s0_[i4], A5 = s0_[i5], A6 = s0_[i6], A7 = s0_[i7],
                     A8 = s0_[i8];
        const float4 B0 = s1_[i0], B1 = s1_[i1], B2 = s1_[i2], B3 = s1_[i3],
                     B4 = s1_[i4], B5 = s1_[i5], B6 = s1_[i6], B7 = s1_[i7],
                     B8 = s1_[i8];
        __builtin_amdgcn_sched_barrier(0);    // keep all loads above compute

        const int lo_u = flo - a0;
        const int hi_u = fhi - a0;
        float* outA = out + (size_t)b0 * ROWELEMS + e0;
        float* outB = outA + ROWELEMS;
        const bool fadeq = (c == TASKS_PER_ROW - 1);
        const int bin0 = 8 * c;

        switch (p) {
            case 0:  pipeline2<0>(A0,A1,A2,A3,A4,A5,A6,A7,A8,
                                  B0,B1,B2,B3,B4,B5,B6,B7,B8,
                                  a0, A, lo_u, hi_u, u1,u2,u3,u4,
                                  fadeq, bin0, outA, outB, color, b0,
                                  p_amount, p_spread); break;
            case 1:  pipeline2<1>(A0,A1,A2,A3,A4,A5,A6,A7,A8,
                                  B0,B1,B2,B3,B4,B5,B6,B7,B8,
                                  a0, A, lo_u, hi_u, u1,u2,u3,u4,
                                  fadeq, bin0, outA, outB, color, b0,
                                  p_amount, p_spread); break;
            case 2:  pipeline2<2>(A0,A1,A2,A3,A4,A5,A6,A7,A8,
                                  B0,B1,B2,B3,B4,B5,B6,B7,B8,
                                  a0, A, lo_u, hi_u, u1,u2,u3,u4,
                                  fadeq, bin0, outA, outB, color, b0,
                                  p_amount, p_spread); break;
            default: pipeline2<3>(A0,A1,A2,A3,A4,A5,A6,A7,A8,
                                  B0,B1,B2,B3,B4,B5,B6,B7,B8,
                                  a0, A, lo_u, hi_u, u1,u2,u3,u4,
                                  fadeq, bin0, outA, outB, color, b0,
                                  p_amount, p_spread); break;
        }
    } else {
        // ============ fixup region: c==0, one row/thread, with injection ============
        const int b = (blockIdx.x - NBLOCKS_MAIN) * NTHREADS + threadIdx.x;
        const int A = -6 - 3 * dfl;
        if (A >= 15) return;                  // main owns c==0 then
        const int p  = A & 3;
        const int a0 = A - p;
        const int q0 = a0 >> 2;

        const float4* src4 = (const float4*)hist + (size_t)b * ROWF4;
        #define CLQ(q) min(max(q0 + (q), 0), ROWF4 - 1)
        const float4 v0 = src4[CLQ(0)], v1 = src4[CLQ(1)], v2 = src4[CLQ(2)],
                     v3 = src4[CLQ(3)], v4 = src4[CLQ(4)], v5 = src4[CLQ(5)],
                     v6 = src4[CLQ(6)], v7 = src4[CLQ(7)], v8 = src4[CLQ(8)];
        #undef CLQ

        float w[36];
        fill24(w, v0, v1, v2, v3, v4, v5);
        fillhi(w, v6, v7, v8);

        const float am = fminf(fmaxf(*p_amount, 0.0f), 1.0f);
        const float sp = fminf(fmaxf(*p_spread, 0.0f), 1.0f);
        const float tight = 1.0f - sp;
        injseg<0, 36>(w, a0, color, b,
                      am * fmaf(0.4f, tight, 0.5f), am * fmaf(0.2f, sp, 0.05f),
                      am * (0.12f * sp), am * (0.06f * sp), am * (0.02f * sp));

        const int lo_u = flo - a0;
        const int hi_u = fhi - a0;
        maskclamp<0, 36>(w, lo_u, hi_u);

        float* outp = out + (size_t)b * ROWELEMS;   // e0 = 0
        switch (p) {
            case 0:  st12<0,0>(w, u1,u2,u3,u4, outp, false, 0);
                     st12<0,1>(w, u1,u2,u3,u4, outp, false, 0); break;
            case 1:  st12<1,0>(w, u1,u2,u3,u4, outp, false, 0);
                     st12<1,1>(w, u1,u2,u3,u4, outp, false, 0); break;
            case 2:  st12<2,0>(w, u1,u2,u3,u4, outp, false, 0);
                     st12<2,1>(w, u1,u2,u3,u4, outp, false, 0); break;
            default: st12<3,0>(w, u1,u2,u3,u4, outp, false, 0);
                     st12<3,1>(w, u1,u2,u3,u4, outp, false, 0); break;
        }
    }
}

extern "C" void kernel_launch(void* const* d_in, const int* in_sizes, int n_in,
                              void* d_out, int out_size, void* d_ws, size_t ws_size,
                              hipStream_t stream) {
    const float* hist      = (const float*)d_in[0];
    const float* color     = (const float*)d_in[1];
    const float* p_offset  = (const float*)d_in[2];
    const float* p_persist = (const float*)d_in[3];
    const float* p_diff    = (const float*)d_in[4];
    const float* p_dt      = (const float*)d_in[5];
    const float* p_amount  = (const float*)d_in[6];
    const float* p_spread  = (const float*)d_in[7];
    float* outp = (float*)d_out;

    beat_kernel<<<dim3(NBLOCKS_MAIN + NBLOCKS_FIX), dim3(NTHREADS), 0, stream>>>(
        hist, color, p_offset, p_persist, p_diff, p_dt, p_amount, p_spread, outp);
}

// Round 9
// 254.115 us; speedup vs baseline: 1.0877x; 1.0877x over previous
//
#include <hip/hip_runtime.h>
#include <math.h>

#define RBINS 160
#define BROWS 65536
#define ROWELEMS 480                    // 160 bins * 3 channels
#define ROWF4 120
#define TPR 40                          // 12-output tasks per row
#define NTHREADS 256
#define ITERS 4
#define TOTAL12 (BROWS * TPR)                        // 2,621,440
#define NBLOCKS_MAIN (TOTAL12 / (NTHREADS * ITERS))  // 2560
#define TSTRIDE (NBLOCKS_MAIN * NTHREADS)            // 655,360
#define NBLOCKS_FIX ((BROWS * 2) / NTHREADS)         // 512

__device__ __forceinline__ float clamp01(float x) {
    return __builtin_amdgcn_fmed3f(x, 0.0f, 1.0f);
}

__device__ __forceinline__ void fill24(
    float* __restrict__ w,
    float4 v0, float4 v1, float4 v2, float4 v3, float4 v4, float4 v5)
{
    w[0]=v0.x;  w[1]=v0.y;  w[2]=v0.z;  w[3]=v0.w;
    w[4]=v1.x;  w[5]=v1.y;  w[6]=v1.z;  w[7]=v1.w;
    w[8]=v2.x;  w[9]=v2.y;  w[10]=v2.z; w[11]=v2.w;
    w[12]=v3.x; w[13]=v3.y; w[14]=v3.z; w[15]=v3.w;
    w[16]=v4.x; w[17]=v4.y; w[18]=v4.z; w[19]=v4.w;
    w[20]=v5.x; w[21]=v5.y; w[22]=v5.z; w[23]=v5.w;
}

// mask + clamp (indices compile-time per element)
__device__ __forceinline__ void maskclamp24(
    float* __restrict__ w, int lo_u, int hi_u)
{
    #pragma unroll
    for (int u = 0; u < 24; ++u) {
        const bool v = (u >= lo_u) && (u < hi_u);
        w[u] = v ? clamp01(w[u]) : 0.0f;
    }
}

// injection of the 5-bin spread kernel into window elements f in [0,15)
__device__ __forceinline__ void inject24w(
    float* __restrict__ w, int a0,
    const float* __restrict__ color, int b,
    float aw0, float aw1, float aw2, float aw3, float aw4)
{
    const float c0 = color[3*b+0];
    const float c1 = color[3*b+1];
    const float c2 = color[3*b+2];
    #pragma unroll
    for (int u = 0; u < 24; ++u) {
        const int f = a0 + u;
        if ((unsigned)f < 15u) {
            const int bin = f / 3;
            const int ch  = f - 3 * bin;
            const float cv = (ch == 0) ? c0 : (ch == 1) ? c1 : c2;
            const float av = (bin == 0) ? aw0 : (bin == 1) ? aw1 :
                             (bin == 2) ? aw2 : (bin == 3) ? aw3 : aw4;
            w[u] += cv * av;
        }
    }
}

// 12-output 4-tap stencil; P = wave-uniform misalignment (compile-time)
template<int P>
__device__ __forceinline__ void stencil12(
    const float* __restrict__ w,
    float u1, float u2, float u3, float u4,
    float* __restrict__ r)
{
    #pragma unroll
    for (int m = 0; m < 12; ++m) {
        float acc = u1 * w[P + m];
        acc = fmaf(u2, w[P + m + 3], acc);
        acc = fmaf(u3, w[P + m + 6], acc);
        acc = fmaf(u4, w[P + m + 9], acc);
        r[m] = acc;
    }
}

__device__ __forceinline__ void loads6(
    const float* __restrict__ hist, int b, int q0,
    float4& v0, float4& v1, float4& v2, float4& v3, float4& v4, float4& v5)
{
    const float4* s = (const float4*)hist + (size_t)b * ROWF4;
    v0 = s[min(max(q0 + 0, 0), ROWF4 - 1)];
    v1 = s[min(max(q0 + 1, 0), ROWF4 - 1)];
    v2 = s[min(max(q0 + 2, 0), ROWF4 - 1)];
    v3 = s[min(max(q0 + 3, 0), ROWF4 - 1)];
    v4 = s[min(max(q0 + 4, 0), ROWF4 - 1)];
    v5 = s[min(max(q0 + 5, 0), ROWF4 - 1)];
}

// full 12-output task: fill, (rare) inject, mask, stencil, fade, store burst
template<int P>
__device__ __forceinline__ void comp12(
    float4 v0, float4 v1, float4 v2, float4 v3, float4 v4, float4 v5,
    int lo_u, int hi_u,
    float u1, float u2, float u3, float u4,
    bool doinj, int a0, const float* __restrict__ color, int b,
    float aw0, float aw1, float aw2, float aw3, float aw4,
    bool dostore, bool fadeq, int bin0, float* __restrict__ outp)
{
    float w[24];
    fill24(w, v0, v1, v2, v3, v4, v5);
    if (doinj) inject24w(w, a0, color, b, aw0, aw1, aw2, aw3, aw4);
    maskclamp24(w, lo_u, hi_u);
    float r[12];
    stencil12<P>(w, u1, u2, u3, u4, r);
    if (fadeq) {
        #pragma unroll
        for (int mb = 0; mb < 4; ++mb) {
            const int j = bin0 + mb;
            const float t = (float)(RBINS - 1 - j) * 0.125f;
            const float ff = (j >= RBINS - 8) ? t * t : 1.0f;
            r[3*mb+0] *= ff; r[3*mb+1] *= ff; r[3*mb+2] *= ff;
        }
    }
    if (dostore) {
        *(float4*)(outp + 0) = make_float4(r[0], r[1], r[2],  r[3]);
        *(float4*)(outp + 4) = make_float4(r[4], r[5], r[6],  r[7]);
        *(float4*)(outp + 8) = make_float4(r[8], r[9], r[10], r[11]);
    }
}

__device__ __forceinline__ void geo(
    int t, int K, int flo, int fhi,
    int& b, int& c, int& q0, int& a0, int& lo, int& hi)
{
    b  = t / TPR;
    c  = t - b * TPR;
    q0 = 3 * c - K;
    a0 = 4 * q0;
    lo = flo - a0;
    hi = fhi - a0;
}

// straight-line 4-task pipeline, prefetch depth 1
template<int P>
__device__ __forceinline__ void mainbody(
    int t0, const float* __restrict__ hist, const float* __restrict__ color,
    float* __restrict__ out, int K, int flo, int fhi,
    float u1, float u2, float u3, float u4,
    float aw0, float aw1, float aw2, float aw3, float aw4)
{
    int bA, cA, qA, aA, loA, hiA;
    int bB, cB, qB, aB, loB, hiB;
    float4 x0, x1, x2, x3, x4, x5;
    float4 y0, y1, y2, y3, y4, y5;

    // task 0 loads
    geo(t0, K, flo, fhi, bA, cA, qA, aA, loA, hiA);
    loads6(hist, bA, qA, x0, x1, x2, x3, x4, x5);

    // prefetch task 1; compute task 0
    geo(t0 + TSTRIDE, K, flo, fhi, bB, cB, qB, aB, loB, hiB);
    loads6(hist, bB, qB, y0, y1, y2, y3, y4, y5);
    __builtin_amdgcn_sched_barrier(0);
    {
        const int Af = aA + P;
        const bool inj = (Af < 15) && (cA >= 2);
        const bool dst = !((Af < 15) && (cA < 2));
        comp12<P>(x0, x1, x2, x3, x4, x5, loA, hiA, u1, u2, u3, u4,
                  inj, aA, color, bA, aw0, aw1, aw2, aw3, aw4,
                  dst, cA >= 38, 4 * cA,
                  out + (size_t)bA * ROWELEMS + 12 * cA);
    }

    // prefetch task 2; compute task 1
    geo(t0 + 2 * TSTRIDE, K, flo, fhi, bA, cA, qA, aA, loA, hiA);
    loads6(hist, bA, qA, x0, x1, x2, x3, x4, x5);
    __builtin_amdgcn_sched_barrier(0);
    {
        const int Af = aB + P;
        const bool inj = (Af < 15) && (cB >= 2);
        const bool dst = !((Af < 15) && (cB < 2));
        comp12<P>(y0, y1, y2, y3, y4, y5, loB, hiB, u1, u2, u3, u4,
                  inj, aB, color, bB, aw0, aw1, aw2, aw3, aw4,
                  dst, cB >= 38, 4 * cB,
                  out + (size_t)bB * ROWELEMS + 12 * cB);
    }

    // prefetch task 3; compute task 2
    geo(t0 + 3 * TSTRIDE, K, flo, fhi, bB, cB, qB, aB, loB, hiB);
    loads6(hist, bB, qB, y0, y1, y2, y3, y4, y5);
    __builtin_amdgcn_sched_barrier(0);
    {
        const int Af = aA + P;
        const bool inj = (Af < 15) && (cA >= 2);
        const bool dst = !((Af < 15) && (cA < 2));
        comp12<P>(x0, x1, x2, x3, x4, x5, loA, hiA, u1, u2, u3, u4,
                  inj, aA, color, bA, aw0, aw1, aw2, aw3, aw4,
                  dst, cA >= 38, 4 * cA,
                  out + (size_t)bA * ROWELEMS + 12 * cA);
    }

    // compute task 3
    {
        const int Af = aB + P;
        const bool inj = (Af < 15) && (cB >= 2);
        const bool dst = !((Af < 15) && (cB < 2));
        comp12<P>(y0, y1, y2, y3, y4, y5, loB, hiB, u1, u2, u3, u4,
                  inj, aB, color, bB, aw0, aw1, aw2, aw3, aw4,
                  dst, cB >= 38, 4 * cB,
                  out + (size_t)bB * ROWELEMS + 12 * cB);
    }
}

__global__ __launch_bounds__(NTHREADS, 4) void beat_kernel(
    const float* __restrict__ hist,
    const float* __restrict__ color,
    const float* __restrict__ p_offset,
    const float* __restrict__ p_persist,
    const float* __restrict__ p_diff,
    const float* __restrict__ p_dt,
    const float* __restrict__ p_amount,
    const float* __restrict__ p_spread,
    float* __restrict__ out)
{
    // ---- wave-uniform parameter math (mirrors ref f32 ops) ----
    const float offs = *p_offset;
    const float pers = *p_persist;
    const float diff = *p_diff;
    const float dts  = *p_dt;

    const float dt       = fminf(fmaxf(dts, 0.0f), 0.05f);
    const float dt_scale = dt * 60.0f;
    const float s        = offs * dt_scale;
    const float dt_pers  = __powf(pers, dt_scale);
    const int   dfl      = (int)floorf(s);
    const float frac     = s - (float)dfl;    // uniform: floor(i+s)=i+dfl interior
    const float kk = 0.15f * diff;
    const float cc = 1.0f - 2.0f * kk;
    const float wl = (1.0f - frac) * dt_pers;
    const float wr = frac * dt_pers;
    const float u1 = wr * kk;
    const float u2 = fmaf(wl, kk, wr * cc);
    const float u3 = fmaf(wl, cc, wr * kk);
    const float u4 = wl * kk;

    // valid source range as element range [flo, fhi)
    const int ilo = max(0, (int)ceilf(-s));
    const int ihi = min(RBINS - 1, (int)ceilf((float)(RBINS - 1) - s) - 1);
    const int flo = 3 * ilo;
    const int fhi = 3 * ihi + 3;

    const int S = 6 + 3 * dfl;                // A = 12c - S
    const int p = (-S) & 3;                   // wave-uniform misalignment
    const int K = (S + p) >> 2;               // q0 = 3c - K

    // injection weights (uniform, cheap; used by rare main path + fixup)
    const float am = fminf(fmaxf(*p_amount, 0.0f), 1.0f);
    const float sp = fminf(fmaxf(*p_spread, 0.0f), 1.0f);
    const float tight = 1.0f - sp;
    const float aw0 = am * fmaf(0.4f, tight, 0.5f);
    const float aw1 = am * fmaf(0.2f, sp, 0.05f);
    const float aw2 = am * (0.12f * sp);
    const float aw3 = am * (0.06f * sp);
    const float aw4 = am * (0.02f * sp);

    if (blockIdx.x < NBLOCKS_MAIN) {
        const int t0 = blockIdx.x * NTHREADS + threadIdx.x;
        switch (p) {
            case 0:  mainbody<0>(t0, hist, color, out, K, flo, fhi,
                                 u1,u2,u3,u4, aw0,aw1,aw2,aw3,aw4); break;
            case 1:  mainbody<1>(t0, hist, color, out, K, flo, fhi,
                                 u1,u2,u3,u4, aw0,aw1,aw2,aw3,aw4); break;
            case 2:  mainbody<2>(t0, hist, color, out, K, flo, fhi,
                                 u1,u2,u3,u4, aw0,aw1,aw2,aw3,aw4); break;
            default: mainbody<3>(t0, hist, color, out, K, flo, fhi,
                                 u1,u2,u3,u4, aw0,aw1,aw2,aw3,aw4); break;
        }
    } else {
        // ---- fixup: c in {0,1}, with injection (owns A<15 tasks) ----
        const int t = (blockIdx.x - NBLOCKS_MAIN) * NTHREADS + threadIdx.x;
        const int b = t >> 1;
        const int c = t & 1;
        const int A = 12 * c - S;
        if (A >= 15) return;                  // main owns this task then
        int bb, cc2, q0, a0, lo, hi;
        geo(b * TPR + c, K, flo, fhi, bb, cc2, q0, a0, lo, hi);
        float4 v0, v1, v2, v3, v4, v5;
        loads6(hist, b, q0, v0, v1, v2, v3, v4, v5);
        float* outp = out + (size_t)b * ROWELEMS + 12 * c;
        switch (p) {
            case 0:  comp12<0>(v0,v1,v2,v3,v4,v5, lo, hi, u1,u2,u3,u4,
                               true, a0, color, b, aw0,aw1,aw2,aw3,aw4,
                               true, false, 4*c, outp); break;
            case 1:  comp12<1>(v0,v1,v2,v3,v4,v5, lo, hi, u1,u2,u3,u4,
                               true, a0, color, b, aw0,aw1,aw2,aw3,aw4,
                               true, false, 4*c, outp); break;
            case 2:  comp12<2>(v0,v1,v2,v3,v4,v5, lo, hi, u1,u2,u3,u4,
                               true, a0, color, b, aw0,aw1,aw2,aw3,aw4,
                               true, false, 4*c, outp); break;
            default: comp12<3>(v0,v1,v2,v3,v4,v5, lo, hi, u1,u2,u3,u4,
                               true, a0, color, b, aw0,aw1,aw2,aw3,aw4,
                               true, false, 4*c, outp); break;
        }
    }
}

extern "C" void kernel_launch(void* const* d_in, const int* in_sizes, int n_in,
                              void* d_out, int out_size, void* d_ws, size_t ws_size,
                              hipStream_t stream) {
    const float* hist      = (const float*)d_in[0];
    const float* color     = (const float*)d_in[1];
    const float* p_offset  = (const float*)d_in[2];
    const float* p_persist = (const float*)d_in[3];
    const float* p_diff    = (const float*)d_in[4];
    const float* p_dt      = (const float*)d_in[5];
    const float* p_amount  = (const float*)d_in[6];
    const float* p_spread  = (const float*)d_in[7];
    float* outp = (float*)d_out;

    beat_kernel<<<dim3(NBLOCKS_MAIN + NBLOCKS_FIX), dim3(NTHREADS), 0, stream>>>(
        hist, color, p_offset, p_persist, p_diff, p_dt, p_amount, p_spread, outp);
}